// Round 11
// baseline (542.141 us; speedup 1.0000x reference)
//
#include <hip/hip_runtime.h>
#include <hip/hip_bf16.h>

typedef __bf16 bf16_t;
typedef __bf16 bf16x4 __attribute__((ext_vector_type(4)));
typedef __bf16 bf16x8 __attribute__((ext_vector_type(8)));
typedef float f32x4 __attribute__((ext_vector_type(4)));

#define GLOAD_LDS16(g, l)                                                      \
  __builtin_amdgcn_global_load_lds(                                            \
      (const __attribute__((address_space(1))) void*)(g),                      \
      (__attribute__((address_space(3))) void*)(l), 16, 0, 0)

#define MFMA(a, b, c) __builtin_amdgcn_mfma_f32_16x16x32_bf16((a), (b), (c), 0, 0, 0)

// ---------------------------------------------------------------------------
// ROUND 11: consolidation. r6/r8 GEMM geometry (best live: 550) + r9's
// minimal-sync loop ending + Nc parameterization + TW=T@W precompute
// (step1 at K=512) + preamble trim.
//
// Cross-round finding: five different K-loop structures all land at
// 91-105 us live per K=1024 step (rocprof dur_us is distorted 1.1-2x by
// replay; live total is ground truth). Walls: MFMA ~33us, LDS-read
// ~41-56us, HBM ~25us, L3-stream ~30-50us -> composite memory wall.
// Schedule churn is negative-EV; bank the algorithmic wins.
//
// Geometry: BM=256 x BN=128, BK=64, 512 thr, 8 waves 4Mx2N, wave-tile
// 64x64 (acc 64 VGPR -> 88 total, no cliff). LDS 3 rotating bufs x 24KB
// = 144KB, 1 block/CU. Iter t: issue all 6 stage loads (tile t+2) early,
// plain ds_read fragments (compiler inserts counted lgkm waits), 32 MFMA,
// then vmcnt(6) (= tile t+1 landed, t+2 flying; never 0) + RAW s_barrier
// (no compiler vmcnt(0)/lgkmcnt(0) drain; r9-validated).
// Swizzle: 16B unit ^ (row&7) on pre-swizzled GLOBAL source, linear LDS
// dest (m173); frag reads (ks*4+kg)^(R&7). Measured 0 conflicts.
//
// u-only LISTA with T = I - S:  u' = soft_thresh(T@u) + Wx
// mode 0: UnextOrWx = bf16(acc)            (Wx / TW GEMMs; Nc = row stride)
// mode 1: UnextOrWx = bf16(soft_thresh(acc) + WxIn)
// mode 2: z = soft_thresh(acc); fused transpose-write Out[b][k][p]
// ---------------------------------------------------------------------------
__global__ __launch_bounds__(512, 2) void gemm_kernel(
    const bf16_t* __restrict__ A, const bf16_t* __restrict__ Bt,
    int Kd, int Nc, int mode,
    const bf16_t* __restrict__ WxIn, bf16_t* __restrict__ UnextOrWx,
    float* __restrict__ Out, const float* __restrict__ thresh_p)
{
  __shared__ __align__(16) char smem[147456];
  bf16_t* lds = (bf16_t*)smem;           // buf stride 24576 elems; B at +16384

  const int tid = threadIdx.x;
  const int wid = tid >> 6, lane = tid & 63;
  const int wr = wid >> 1, wc = wid & 1;         // 4M x 2N wave grid
  const int lr = lane & 15, kg = lane >> 4;

  // XCD-chunked swizzle (grid % 8 == 0), N-fastest: consecutive logical
  // blocks share the A row-panel; B (T, 2MiB) is L2-resident.
  const int per = gridDim.x >> 3;
  const int logical = (blockIdx.x & 7) * per + (blockIdx.x >> 3);
  const int ntn = Nc >> 7;
  const int tileN = (logical % ntn) << 7;
  const int tileM = (logical / ntn) << 8;
  const int NT = Kd >> 6;

  // Per-thread staging geometry (A: 4 rounds, B: 2 rounds of 16B units;
  // row = 64 bf16 = 8 units, unit ^= (row&7) on the global source).
  size_t offA[4]; int dstA[4];
  #pragma unroll
  for (int j = 0; j < 4; ++j) {
    const int f = j * 512 + tid;                 // 0..2047
    const int row = f >> 3, u = f & 7;
    const int ug = u ^ (row & 7);
    offA[j] = (size_t)(tileM + row) * Kd + ug * 8;
    dstA[j] = f * 8;
  }
  size_t offB[2]; int dstB[2];
  #pragma unroll
  for (int j = 0; j < 2; ++j) {
    const int f = j * 512 + tid;                 // 0..1023
    const int col = f >> 3, u = f & 7;
    const int ug = u ^ (col & 7);
    offB[j] = (size_t)(tileN + col) * Kd + ug * 8;
    dstB[j] = 16384 + f * 8;
  }

  auto readA = [&](int mi, int ks, int bs) -> bf16x8 {
    const int R = wr * 64 + mi * 16 + lr;
    const int ul = (ks * 4 + kg) ^ (R & 7);
    return *(const bf16x8*)(lds + bs + R * 64 + ul * 8);
  };
  auto readB = [&](int ni, int ks, int bs) -> bf16x8 {
    const int C = wc * 64 + ni * 16 + lr;
    const int ul = (ks * 4 + kg) ^ (C & 7);
    return *(const bf16x8*)(lds + bs + 16384 + C * 64 + ul * 8);
  };

  f32x4 acc[4][4] = {};
  bf16x8 a0[4], b0[4], a1[4], b1[4];

  // Prologue: stage tiles 0 and 1 (6 loads each).
  #pragma unroll
  for (int j = 0; j < 4; ++j) GLOAD_LDS16(A + offA[j], lds + dstA[j]);
  #pragma unroll
  for (int j = 0; j < 2; ++j) GLOAD_LDS16(Bt + offB[j], lds + dstB[j]);
  if (NT > 1) {
    #pragma unroll
    for (int j = 0; j < 4; ++j) GLOAD_LDS16(A + offA[j] + 64, lds + 24576 + dstA[j]);
    #pragma unroll
    for (int j = 0; j < 2; ++j) GLOAD_LDS16(Bt + offB[j] + 64, lds + 24576 + dstB[j]);
  }
  asm volatile("s_waitcnt vmcnt(6)" ::: "memory");   // tile 0 landed
  __builtin_amdgcn_s_barrier();

  int buf = 0, sb3 = 2;                              // t%3, (t+2)%3
  for (int t = 0; t < NT; ++t) {
    const int bs = buf * 24576;
    const int sbs = sb3 * 24576;
    const int ts = (t + 2 < NT) ? t + 2 : t + 2 - NT;   // wrap refetch (benign)
    const size_t ko = (size_t)ts << 6;

    // Issue-early: all 6 stage loads for tile t+2.
    GLOAD_LDS16(A + offA[0] + ko, lds + sbs + dstA[0]);
    GLOAD_LDS16(A + offA[1] + ko, lds + sbs + dstA[1]);
    GLOAD_LDS16(A + offA[2] + ko, lds + sbs + dstA[2]);
    GLOAD_LDS16(A + offA[3] + ko, lds + sbs + dstA[3]);
    GLOAD_LDS16(Bt + offB[0] + ko, lds + sbs + dstB[0]);
    GLOAD_LDS16(Bt + offB[1] + ko, lds + sbs + dstB[1]);

    // Fragments (plain LDS loads; compiler schedules counted lgkm waits;
    // independent ks0/ks1 regs let ks0-MFMA overlap ks1-reads).
    #pragma unroll
    for (int mi = 0; mi < 4; ++mi) a0[mi] = readA(mi, 0, bs);
    #pragma unroll
    for (int ni = 0; ni < 4; ++ni) b0[ni] = readB(ni, 0, bs);
    #pragma unroll
    for (int mi = 0; mi < 4; ++mi) a1[mi] = readA(mi, 1, bs);
    #pragma unroll
    for (int ni = 0; ni < 4; ++ni) b1[ni] = readB(ni, 1, bs);

    #pragma unroll
    for (int mi = 0; mi < 4; ++mi)
      #pragma unroll
      for (int ni = 0; ni < 4; ++ni)
        acc[mi][ni] = MFMA(a0[mi], b0[ni], acc[mi][ni]);
    #pragma unroll
    for (int mi = 0; mi < 4; ++mi)
      #pragma unroll
      for (int ni = 0; ni < 4; ++ni)
        acc[mi][ni] = MFMA(a1[mi], b1[ni], acc[mi][ni]);

    asm volatile("s_waitcnt vmcnt(6)" ::: "memory");   // tile t+1 landed
    __builtin_amdgcn_s_barrier();                      // raw: no drain

    buf = (buf == 2) ? 0 : buf + 1;
    sb3 = (sb3 == 2) ? 0 : sb3 + 1;
  }

  const float th = *thresh_p;

  if (mode <= 1) {
    // Repack epilogue: canonical row-major bf16, 8B/lane full-line stores.
    asm volatile("s_waitcnt vmcnt(0)" ::: "memory");   // wrap stages landed
    __syncthreads();
    float* Tl = (float*)smem;                          // [32][132] f32
    #pragma unroll
    for (int c = 0; c < 8; ++c) {                      // 32-row chunks
      if (c) __syncthreads();
      if (wr == (c >> 1)) {
        #pragma unroll
        for (int mj = 0; mj < 2; ++mj) {
          const int mi = (c & 1) * 2 + mj;
          const int rl = mj * 16 + kg * 4;
          #pragma unroll
          for (int ni = 0; ni < 4; ++ni) {
            const int cl = wc * 64 + ni * 16 + lr;
            #pragma unroll
            for (int r = 0; r < 4; ++r)
              Tl[(rl + r) * 132 + cl] = acc[mi][ni][r];
          }
        }
      }
      __syncthreads();
      #pragma unroll
      for (int j = 0; j < 2; ++j) {
        const int f  = j * 512 + tid;                  // 0..1023
        const int rl = f >> 5;                         // 0..31
        const int c4 = (f & 31) * 4;                   // 0..124
        const f32x4 v = *(const f32x4*)&Tl[rl * 132 + c4];
        const int grow = tileM + c * 32 + rl;
        const size_t gidx = (size_t)grow * Nc + tileN + c4;
        bf16x4 ov;
        if (mode == 1) {
          const bf16x4 wx = *(const bf16x4*)&WxIn[gidx];
          #pragma unroll
          for (int e = 0; e < 4; ++e) {
            const float a  = fabsf(v[e]) - th;
            const float zn = (a > 0.f) ? copysignf(a, v[e]) : 0.f;
            ov[e] = (bf16_t)(zn + (float)wx[e]);
          }
        } else {
          #pragma unroll
          for (int e = 0; e < 4; ++e) ov[e] = (bf16_t)v[e];
        }
        *(bf16x4*)&UnextOrWx[gidx] = ov;
      }
    }
  } else {
    // mode 2 (Nc==1024): z = st(acc), fused transpose -> Out[b][k][p].
    #pragma unroll
    for (int mi = 0; mi < 4; ++mi)
      #pragma unroll
      for (int ni = 0; ni < 4; ++ni)
        #pragma unroll
        for (int r = 0; r < 4; ++r) {
          const float v = acc[mi][ni][r];
          const float a = fabsf(v) - th;
          acc[mi][ni][r] = (a > 0.f) ? copysignf(a, v) : 0.f;
        }
    asm volatile("s_waitcnt vmcnt(0)" ::: "memory");
    __syncthreads();
    float* Tl = (float*)smem;                          // [32][260] f32
    const int    bb    = tileM >> 10;
    const size_t obase = (size_t)bb * 1048576 + (size_t)(tileM & 1023);
    #pragma unroll
    for (int ch = 0; ch < 4; ++ch) {                   // 32-k-col chunks
      if (ch) __syncthreads();
      if (wc == (ch >> 1)) {
        #pragma unroll
        for (int nj = 0; nj < 2; ++nj) {
          const int ni = (ch & 1) * 2 + nj;
          const int cp = nj * 16 + lr;                 // 0..31
          #pragma unroll
          for (int mi = 0; mi < 4; ++mi)
            #pragma unroll
            for (int r = 0; r < 4; ++r)
              Tl[cp * 260 + wr * 64 + mi * 16 + kg * 4 + r] = acc[mi][ni][r];
        }
      }
      __syncthreads();
      #pragma unroll
      for (int j = 0; j < 4; ++j) {
        const int f  = j * 512 + tid;                  // 0..2047
        const int cp = f >> 6;                         // 0..31
        const int p4 = (f & 63) * 4;                   // 0..252
        const f32x4 v = *(const f32x4*)&Tl[cp * 260 + p4];
        *(f32x4*)&Out[obase + (size_t)(tileN + ch * 32 + cp) * 1024 + p4] = v;
      }
    }
  }
}

// Fused: T = bf16(I - S) over [1024][1024], and Wbf = bf16(W) for idx<512k.
__global__ void make_T_castW_kernel(const float* __restrict__ S,
                                    bf16_t* __restrict__ T,
                                    const float* __restrict__ W,
                                    bf16_t* __restrict__ Wb) {
  const int idx = blockIdx.x * blockDim.x + threadIdx.x;   // 0..1048575
  const int i = idx >> 10, j = idx & 1023;
  T[idx] = (bf16_t)(((i == j) ? 1.0f : 0.0f) - S[idx]);
  if (idx < 524288) Wb[idx] = (bf16_t)W[idx];
}

// x [B][C=512][P=1024] f32 -> xt [b*1024+p][c] bf16
__global__ void transpose_cast_x_kernel(const float* __restrict__ x,
                                        bf16_t* __restrict__ xt) {
  __shared__ float t[32][33];
  const int b  = blockIdx.z;
  const int p0 = blockIdx.x * 32;
  const int c0 = blockIdx.y * 32;
  const int tx = threadIdx.x, ty = threadIdx.y;
  #pragma unroll
  for (int i = 0; i < 32; i += 8)
    t[ty + i][tx] = x[((size_t)b * 512 + c0 + ty + i) * 1024 + p0 + tx];
  __syncthreads();
  #pragma unroll
  for (int i = 0; i < 32; i += 8)
    xt[((size_t)b * 1024 + p0 + ty + i) * 512 + c0 + tx] = (bf16_t)t[tx][ty + i];
}

// Wt[c][j] = W[j][c], f32 [1024][512] -> bf16 [512][1024]
__global__ void transpose_cast_w_kernel(const float* __restrict__ W,
                                        bf16_t* __restrict__ Wt) {
  __shared__ float t[32][33];
  const int j0 = blockIdx.x * 32;
  const int c0 = blockIdx.y * 32;
  const int tx = threadIdx.x, ty = threadIdx.y;
  #pragma unroll
  for (int i = 0; i < 32; i += 8)
    t[ty + i][tx] = W[(size_t)(j0 + ty + i) * 512 + c0 + tx];
  __syncthreads();
  #pragma unroll
  for (int i = 0; i < 32; i += 8)
    Wt[(size_t)(c0 + ty + i) * 1024 + j0 + tx] = (bf16_t)t[tx][ty + i];
}

__global__ void dict_norm_kernel(const float* __restrict__ dict,
                                 float* __restrict__ out) {
  const int row = blockIdx.x;
  const int tid = threadIdx.x;
  const float* r = dict + (size_t)row * 512;
  float s = 0.f;
  for (int i = tid; i < 512; i += 256) { float v = r[i]; s += v * v; }
  #pragma unroll
  for (int off = 32; off > 0; off >>= 1) s += __shfl_down(s, off);
  __shared__ float ps[4];
  if ((tid & 63) == 0) ps[tid >> 6] = s;
  __syncthreads();
  const float inv = 1.0f / sqrtf(ps[0] + ps[1] + ps[2] + ps[3]);
  for (int i = tid; i < 512; i += 256) out[(size_t)row * 512 + i] = r[i] * inv;
}

extern "C" void kernel_launch(void* const* d_in, const int* in_sizes, int n_in,
                              void* d_out, int out_size, void* d_ws, size_t ws_size,
                              hipStream_t stream) {
  const float* x      = (const float*)d_in[0];  // [32,512,32,32]
  const float* dict   = (const float*)d_in[1];  // [1024,512]
  const float* W      = (const float*)d_in[2];  // [1024,512]
  const float* S      = (const float*)d_in[3];  // [1024,1024]
  const float* thresh = (const float*)d_in[4];  // scalar

  float* out = (float*)d_out;

  char* ws = (char*)d_ws;
  bf16_t* uA   = (bf16_t*)ws;                     //  67,108,864 B [32768][1024]
  bf16_t* uB   = (bf16_t*)(ws + 67108864);        //  67,108,864 B
  bf16_t* WxBf = (bf16_t*)(ws + 134217728);       //  67,108,864 B
  bf16_t* xt   = (bf16_t*)(ws + 201326592);       //  33,554,432 B [32768][512]
  bf16_t* Wbf  = (bf16_t*)(ws + 234881024);       //   1,048,576 B
  bf16_t* Tbf  = (bf16_t*)(ws + 235929600);       //   2,097,152 B (end 238,026,752)

  // Temporaries in d_out's z-region (overwritten by mode-2 at the end).
  bf16_t* WtBf = (bf16_t*)out;                    //   1,048,576 B [512][1024]
  bf16_t* TWbf = WtBf + 524288;                   //   1,048,576 B [1024][512]
  float* dnorm = out + 33554432;                  // dict_norm region (disjoint)

  make_T_castW_kernel<<<dim3(2048), dim3(512), 0, stream>>>(S, Tbf, W, Wbf);
  transpose_cast_x_kernel<<<dim3(32, 16, 32), dim3(32, 8), 0, stream>>>(x, xt);
  transpose_cast_w_kernel<<<dim3(32, 16), dim3(32, 8), 0, stream>>>(W, WtBf);
  dict_norm_kernel<<<dim3(1024), dim3(256), 0, stream>>>(dict, dnorm);

  // TW = T @ W  (M=1024, Nc=512, Kd=1024): grid 4x4 = 16 blocks, mode 0.
  gemm_kernel<<<dim3(16), dim3(512), 0, stream>>>(
      Tbf, WtBf, 1024, 512, 0, nullptr, TWbf, nullptr, thresh);

  // Wx = xt @ W^T  (Kd=512, Nc=1024) -> WxBf
  gemm_kernel<<<dim3(1024), dim3(512), 0, stream>>>(
      xt, Wbf, 512, 1024, 0, nullptr, WxBf, nullptr, thresh);

  // step 1 at K=512: u2 = st(TW @ x) + Wx
  gemm_kernel<<<dim3(1024), dim3(512), 0, stream>>>(
      xt, TWbf, 512, 1024, 1, WxBf, uA, nullptr, thresh);

  // steps 2..4: u' = st(T@u) + Wx
  bf16_t* uc = uA; bf16_t* un = uB;
  for (int s = 0; s < 3; ++s) {
    gemm_kernel<<<dim3(1024), dim3(512), 0, stream>>>(
        uc, Tbf, 1024, 1024, 1, WxBf, un, nullptr, thresh);
    bf16_t* tmp = uc; uc = un; un = tmp;
  }
  // step 5: z = st(T@u), fused transpose to out[b][k][p]
  gemm_kernel<<<dim3(1024), dim3(512), 0, stream>>>(
      uc, Tbf, 1024, 1024, 2, nullptr, nullptr, out, thresh);
}